// Round 6
// baseline (1641.016 us; speedup 1.0000x reference)
//
#include <hip/hip_runtime.h>
#include <hip/hip_fp16.h>
#include <math.h>

#define L 1024
#define BATCH 32
#define TS 64
#define PADU 66
#define NT 16
#define NPAIRS 136
#define STEPS 20
#define NTASK (NPAIRS*BATCH)   // 4352
#define GRID 2048

struct __align__(8) us4 { unsigned short x, y, z, w; };
typedef float vf4 __attribute__((ext_vector_type(4)));

__device__ __forceinline__ float4 ld4(const float* p){ return *(const float4*)p; }
__device__ __forceinline__ void st4_nt(float* p, float a, float b, float c, float d){
  vf4 v; v.x = a; v.y = b; v.z = c; v.w = d;
  __builtin_nontemporal_store(v, (vf4*)p);
}
__device__ __forceinline__ unsigned short f2h(float x){
  __half h = __float2half(x);
  return *(unsigned short*)&h;
}
__device__ __forceinline__ float h2f(unsigned short u){
  __half h; *(unsigned short*)&h = u;
  return __half2float(h);
}
__device__ __forceinline__ float red16(float v){
  v += __shfl_xor(v, 1); v += __shfl_xor(v, 2);
  v += __shfl_xor(v, 4); v += __shfl_xor(v, 8);
  return v;
}
__device__ __forceinline__ void decode_pair(int p, int& bi, int& bj){
  bi = 0;
  while (p >= NT - bi){ p -= NT - bi; ++bi; }
  bj = bi + p;
}

// pbuf: [0..19] a_t, [20..39] belt*lr_belt^t, [40] s, [41] w
__global__ void params_kernel(float* pbuf, const float* s, const float* w,
                              const float* alpha, const float* belt,
                              const float* lra, const float* lrb) {
  int t = threadIdx.x;
  if (t < STEPS) {
    pbuf[t]         = alpha[0] * powf(lra[0], (float)t);
    pbuf[STEPS + t] = belt[0]  * powf(lrb[0], (float)t);
  }
  if (t == 0) { pbuf[2*STEPS] = s[0]; pbuf[2*STEPS + 1] = w[0]; }
}

// prep: S_bar = 0.5(sc+scT)-s -> fp16 Sb; optional fp16 Mb; rowsum partials of A0.
template<bool PACKM>
__global__ __launch_bounds__(256, 8)
void prep_kernel(const float* __restrict__ scores, const float* __restrict__ Mm,
                 unsigned short* __restrict__ Sb, unsigned short* __restrict__ Mb,
                 float* __restrict__ rsOut, const float* __restrict__ pbuf)
{
  __shared__ unsigned short buf1[TS*PADU];   // scores_ji fp16 (transposed access)
  __shared__ unsigned short buf2[TS*PADU];   // S_bar fp16 (transposed access)
  const int tid = threadIdx.x, cg = tid & 15, rr = tid >> 4, c4 = cg*4;
  const float sv = pbuf[2*STEPS];

  for (int task = blockIdx.x; task < NTASK; task += GRID){
    const int b = task & (BATCH-1);
    int bi, bj; decode_pair(task >> 5, bi, bj);
    const bool diag = (bi == bj);
    const int ibase = bi*TS, jbase = bj*TS;
    const size_t bb = (size_t)b * L * L;

    #pragma unroll
    for (int it = 0; it < 4; ++it){
      int row = it*16 + rr;
      float4 v = ld4(scores + bb + (size_t)(jbase+row)*L + ibase + c4);
      unsigned short* d = &buf1[row*PADU + c4];
      d[0]=f2h(v.x); d[1]=f2h(v.y); d[2]=f2h(v.z); d[3]=f2h(v.w);
    }
    __syncthreads();

    #pragma unroll
    for (int it = 0; it < 4; ++it){
      int ii = it*16 + rr;
      size_t off = bb + (size_t)(ibase+ii)*L + jbase + c4;
      float4 s4 = ld4(scores + off);
      float4 m4 = ld4(Mm + off);
      float sc[4] = {s4.x,s4.y,s4.z,s4.w};
      float m [4] = {m4.x,m4.y,m4.z,m4.w};
      unsigned short qs[4], qm[4];
      float part = 0.f;
      #pragma unroll
      for (int k = 0; k < 4; ++k){
        float scT = h2f(buf1[(c4+k)*PADU + ii]);
        float sbv = 0.5f*(sc[k] + scT) - sv;
        unsigned short q = f2h(sbv);
        buf2[ii*PADU + c4 + k] = q;
        part += (h2f(q) + sv) * m[k];
        qs[k] = q; qm[k] = f2h(m[k]);
      }
      us4 so = {qs[0],qs[1],qs[2],qs[3]};
      *(us4*)(Sb + off) = so;
      if constexpr (PACKM){ us4 mo = {qm[0],qm[1],qm[2],qm[3]}; *(us4*)(Mb + off) = mo; }
      part = red16(part);
      if (cg == 0) rsOut[((size_t)b*NT + bj)*L + ibase + ii] = part;
    }
    __syncthreads();

    if (!diag){
      #pragma unroll
      for (int it = 0; it < 4; ++it){
        int jj = it*16 + rr;
        size_t off = bb + (size_t)(jbase+jj)*L + ibase + c4;
        float4 m4 = ld4(Mm + off);
        float m[4] = {m4.x,m4.y,m4.z,m4.w};
        unsigned short qs[4], qm[4];
        float part = 0.f;
        #pragma unroll
        for (int k = 0; k < 4; ++k){
          unsigned short q = buf2[(c4+k)*PADU + jj];   // S_bar symmetric
          part += (h2f(q) + sv) * m[k];
          qs[k] = q; qm[k] = f2h(m[k]);
        }
        us4 so = {qs[0],qs[1],qs[2],qs[3]};
        *(us4*)(Sb + off) = so;
        if constexpr (PACKM){ us4 mo = {qm[0],qm[1],qm[2],qm[3]}; *(us4*)(Mb + off) = mo; }
        part = red16(part);
        if (cg == 0) rsOut[((size_t)b*NT + bi)*L + jbase + jj] = part;
      }
    }
    __syncthreads();
  }
}

// one step. FIRST: h from scores, Lm init. LAST: write A=0.5(Hn+HnT)*M_f32 to Hf.
// H16: state carried as fp16 in Hh; else f32 in Hf.
template<bool PACKM, bool H16, bool FIRST, bool LAST>
__global__ __launch_bounds__(256, 8)
void step_kernel(const float* __restrict__ scores,
                 const unsigned short* __restrict__ Sb,
                 const unsigned short* __restrict__ Mb,
                 const float* __restrict__ Mm,
                 const float* __restrict__ rho,
                 float* __restrict__ Hf,
                 unsigned short* __restrict__ Hh,
                 const float* __restrict__ rsIn, float* __restrict__ rsOut,
                 const float* __restrict__ LmIn, float* __restrict__ LmOut,
                 const float* __restrict__ pbuf, const int t)
{
  __shared__ unsigned short bufP[TS*PADU];   // Hn_ij fp16
  __shared__ unsigned short bufQ[TS*PADU];   // Hn_ji fp16
  __shared__ float cbuf[2*TS];

  const int tid = threadIdx.x, cg = tid & 15, rr = tid >> 4, c4 = cg*4;
  const float a_t = pbuf[t];

  for (int task = blockIdx.x; task < NTASK; task += GRID){
    const int b = task & (BATCH-1);
    int bi, bj; decode_pair(task >> 5, bi, bj);
    const bool diag = (bi == bj);
    const int ibase = bi*TS, jbase = bj*TS;
    const size_t bb = (size_t)b * L * L;

    // ---- c phase ----
    if (tid < 128){
      const int half = tid >> 6, lane = tid & 63;
      const int rowbase = half ? jbase : ibase;
      const float* rp = rsIn + (size_t)b*NT*L + rowbase + lane;
      float rs = 0.f;
      #pragma unroll
      for (int pq = 0; pq < NT; ++pq) rs += rp[(size_t)pq * L];
      const float rowm = rs - 1.0f;
      const float rl = fmaxf(rowm, 0.f);
      float lm;
      if constexpr (FIRST) lm = pbuf[2*STEPS+1] * rl;
      else lm = LmIn[(size_t)b*L + rowbase + lane] + pbuf[STEPS + t - 1] * rl;
      const float sg = (rowm > 0.f) ? 1.f : ((rowm < 0.f) ? -1.f : 0.f);
      cbuf[tid] = lm * sg;
      if constexpr (!LAST){ if (half == 0) LmOut[(size_t)b*L + rowbase + lane] = lm; }
    }
    __syncthreads();

    float mR[4][4], hnR[4][4], part1[4];

    // ---- phase A: tile-ij update ----
    #pragma unroll
    for (int it = 0; it < 4; ++it){
      const int ii = it*16 + rr;
      const size_t offr = (size_t)(ibase+ii)*L + jbase + c4;
      const size_t off = bb + offr;
      float h[4];
      if constexpr (FIRST){
        float4 h4 = ld4(scores + off); h[0]=h4.x;h[1]=h4.y;h[2]=h4.z;h[3]=h4.w;
      } else if constexpr (H16){
        us4 hu = *(const us4*)(Hh + off);
        h[0]=h2f(hu.x); h[1]=h2f(hu.y); h[2]=h2f(hu.z); h[3]=h2f(hu.w);
      } else {
        float4 h4 = ld4(Hf + off); h[0]=h4.x;h[1]=h4.y;h[2]=h4.z;h[3]=h4.w;
      }
      float m[4];
      if constexpr (LAST){
        float4 m4 = ld4(Mm + off); m[0]=m4.x;m[1]=m4.y;m[2]=m4.z;m[3]=m4.w;
      } else if constexpr (PACKM){
        us4 mu = *(const us4*)(Mb + off);
        m[0]=h2f(mu.x); m[1]=h2f(mu.y); m[2]=h2f(mu.z); m[3]=h2f(mu.w);
      } else {
        float4 m4 = ld4(Mm + off); m[0]=m4.x;m[1]=m4.y;m[2]=m4.z;m[3]=m4.w;
      }
      us4 su = *(const us4*)(Sb + off);
      float sb[4] = {h2f(su.x),h2f(su.y),h2f(su.z),h2f(su.w)};
      float4 r4 = ld4(rho + offr);
      float rh[4] = {r4.x,r4.y,r4.z,r4.w};
      const float ci = cbuf[ii];
      float p1 = 0.f;
      unsigned short hb[4];
      float hn[4];
      #pragma unroll
      for (int k = 0; k < 4; ++k){
        const float g = sb[k] - ci - cbuf[TS + c4 + k];
        float x = fmaf(a_t * h[k] * m[k], g, h[k]);
        x = fminf(fmaxf(fabsf(x) - rh[k]*a_t, 0.f), 1.f);
        mR[it][k] = m[k];
        unsigned short bits = f2h(x);
        bufP[ii*PADU + c4 + k] = bits;
        if constexpr (LAST){
          hnR[it][k] = x;
        } else if constexpr (H16){
          float xq = h2f(bits);
          hb[k] = bits;
          p1 += 0.5f * xq * m[k];
        } else {
          hn[k] = x;
          p1 += 0.5f * x * m[k];
        }
      }
      if constexpr (!LAST){
        part1[it] = p1;
        if constexpr (H16){
          us4 o = {hb[0],hb[1],hb[2],hb[3]};
          *(us4*)(Hh + off) = o;
        } else {
          float4 o; o.x=hn[0]; o.y=hn[1]; o.z=hn[2]; o.w=hn[3];
          *(float4*)(Hf + off) = o;
        }
      }
    }
    __syncthreads();

    // ---- phase B: tile-ji update ----
    if (!diag){
      #pragma unroll
      for (int it = 0; it < 4; ++it){
        const int jj = it*16 + rr;
        const size_t offr = (size_t)(jbase+jj)*L + ibase + c4;
        const size_t off = bb + offr;
        float h[4];
        if constexpr (FIRST){
          float4 h4 = ld4(scores + off); h[0]=h4.x;h[1]=h4.y;h[2]=h4.z;h[3]=h4.w;
        } else if constexpr (H16){
          us4 hu = *(const us4*)(Hh + off);
          h[0]=h2f(hu.x); h[1]=h2f(hu.y); h[2]=h2f(hu.z); h[3]=h2f(hu.w);
        } else {
          float4 h4 = ld4(Hf + off); h[0]=h4.x;h[1]=h4.y;h[2]=h4.z;h[3]=h4.w;
        }
        float m[4];
        if constexpr (LAST){
          float4 m4 = ld4(Mm + off); m[0]=m4.x;m[1]=m4.y;m[2]=m4.z;m[3]=m4.w;
        } else if constexpr (PACKM){
          us4 mu = *(const us4*)(Mb + off);
          m[0]=h2f(mu.x); m[1]=h2f(mu.y); m[2]=h2f(mu.z); m[3]=h2f(mu.w);
        } else {
          float4 m4 = ld4(Mm + off); m[0]=m4.x;m[1]=m4.y;m[2]=m4.z;m[3]=m4.w;
        }
        us4 su = *(const us4*)(Sb + off);
        float sb[4] = {h2f(su.x),h2f(su.y),h2f(su.z),h2f(su.w)};
        float4 r4 = ld4(rho + offr);
        float rh[4] = {r4.x,r4.y,r4.z,r4.w};
        const float cj = cbuf[TS + jj];
        float part = 0.f;
        unsigned short hb[4];
        float outv[4];
        #pragma unroll
        for (int k = 0; k < 4; ++k){
          const float g = sb[k] - cj - cbuf[c4 + k];
          float x = fmaf(a_t * h[k] * m[k], g, h[k]);
          x = fminf(fmaxf(fabsf(x) - rh[k]*a_t, 0.f), 1.f);
          unsigned short bits = f2h(x);
          bufQ[jj*PADU + c4 + k] = bits;
          if constexpr (LAST){
            float hT = h2f(bufP[(c4+k)*PADU + jj]);
            outv[k] = 0.5f*(x + hT)*m[k];
          } else if constexpr (H16){
            float xq = h2f(bits);
            hb[k] = bits;
            float hT = h2f(bufP[(c4+k)*PADU + jj]);
            part += 0.5f*(xq + hT)*m[k];
          } else {
            float hT = h2f(bufP[(c4+k)*PADU + jj]);
            part += 0.5f*(x + hT)*m[k];
            outv[k] = x;
          }
        }
        if constexpr (LAST){
          st4_nt(Hf + off, outv[0], outv[1], outv[2], outv[3]);
        } else if constexpr (H16){
          us4 o = {hb[0],hb[1],hb[2],hb[3]};
          *(us4*)(Hh + off) = o;
        } else {
          float4 o; o.x=outv[0]; o.y=outv[1]; o.z=outv[2]; o.w=outv[3];
          *(float4*)(Hf + off) = o;
        }
        if constexpr (!LAST){
          part = red16(part);
          if (cg == 0) rsOut[((size_t)b*NT + bi)*L + jbase + jj] = part;
        }
      }
    }
    __syncthreads();

    // ---- phase C: rows-i (partials or final A_ij) ----
    const unsigned short* hs = diag ? bufP : bufQ;
    #pragma unroll
    for (int it = 0; it < 4; ++it){
      const int ii = it*16 + rr;
      if constexpr (LAST){
        float av[4];
        #pragma unroll
        for (int k = 0; k < 4; ++k){
          float hT = h2f(hs[(c4+k)*PADU + ii]);
          av[k] = 0.5f*(hnR[it][k] + hT)*mR[it][k];
        }
        size_t off = bb + (size_t)(ibase+ii)*L + jbase + c4;
        st4_nt(Hf + off, av[0], av[1], av[2], av[3]);
      } else {
        float part = part1[it];
        #pragma unroll
        for (int k = 0; k < 4; ++k)
          part += 0.5f * h2f(hs[(c4+k)*PADU + ii]) * mR[it][k];
        part = red16(part);
        if (cg == 0) rsOut[((size_t)b*NT + bj)*L + ibase + ii] = part;
      }
    }
    __syncthreads();
  }
}

template<bool PACKM, bool H16>
static void run_steps(const float* scores, const unsigned short* Sb,
                      const unsigned short* Mb, const float* Mm, const float* rho,
                      float* Hf, unsigned short* Hh,
                      float** rs, float** lmv, const float* pbuf, hipStream_t stream)
{
  for (int t = 0; t < STEPS; ++t){
    float* rin = rs[t & 1]; float* rout = rs[(t + 1) & 1];
    const float* lin = lmv[(t + 1) & 1]; float* lout = lmv[t & 1];
    if (t == 0)
      step_kernel<PACKM,H16,true ,false><<<GRID,256,0,stream>>>(scores,Sb,Mb,Mm,rho,Hf,Hh,rin,rout,lin,lout,pbuf,t);
    else if (t == STEPS-1)
      step_kernel<PACKM,H16,false,true ><<<GRID,256,0,stream>>>(scores,Sb,Mb,Mm,rho,Hf,Hh,rin,rout,lin,lout,pbuf,t);
    else
      step_kernel<PACKM,H16,false,false><<<GRID,256,0,stream>>>(scores,Sb,Mb,Mm,rho,Hf,Hh,rin,rout,lin,lout,pbuf,t);
  }
}

extern "C" void kernel_launch(void* const* d_in, const int* in_sizes, int n_in,
                              void* d_out, int out_size, void* d_ws, size_t ws_size,
                              hipStream_t stream) {
  const float* scores = (const float*)d_in[0];
  const float* Mm     = (const float*)d_in[1];
  const float* rho    = (const float*)d_in[2];
  const float* s      = (const float*)d_in[3];
  const float* w      = (const float*)d_in[4];
  const float* alpha  = (const float*)d_in[5];
  const float* belt   = (const float*)d_in[6];
  const float* lra    = (const float*)d_in[7];
  const float* lrb    = (const float*)d_in[8];
  float* Hf = (float*)d_out;

  const size_t SBB = (size_t)BATCH*L*L*2;   // fp16 S_bar
  const size_t MBB = (size_t)BATCH*L*L*2;   // fp16 M
  const size_t HHB = (size_t)BATCH*L*L*2;   // fp16 H state
  const size_t RSB = (size_t)BATCH*NT*L*4;
  const size_t LMB = (size_t)BATCH*L*4;
  const size_t need_base = 2*RSB + 2*LMB + 4096;

  char* wp = (char*)d_ws;
  const bool h16   = ws_size >= SBB + MBB + HHB + need_base;
  const bool packm = h16 || (ws_size >= SBB + MBB + need_base);

  size_t off = 0;
  unsigned short* Sb = (unsigned short*)wp; off += SBB;
  unsigned short* Mb = Sb;
  if (packm){ Mb = (unsigned short*)(wp + off); off += MBB; }
  unsigned short* Hh = nullptr;
  if (h16){ Hh = (unsigned short*)(wp + off); off += HHB; }
  float* rs0  = (float*)(wp + off); off += RSB;
  float* rs1  = (float*)(wp + off); off += RSB;
  float* lm0  = (float*)(wp + off); off += LMB;
  float* lm1  = (float*)(wp + off); off += LMB;
  float* pbuf = (float*)(wp + off);

  params_kernel<<<1, 64, 0, stream>>>(pbuf, s, w, alpha, belt, lra, lrb);

  float* rs[2]  = {rs0, rs1};
  float* lmv[2] = {lm0, lm1};

  if (h16){
    prep_kernel<true><<<GRID, 256, 0, stream>>>(scores, Mm, Sb, Mb, rs0, pbuf);
    run_steps<true,true>(scores, Sb, Mb, Mm, rho, Hf, Hh, rs, lmv, pbuf, stream);
  } else if (packm){
    prep_kernel<true><<<GRID, 256, 0, stream>>>(scores, Mm, Sb, Mb, rs0, pbuf);
    run_steps<true,false>(scores, Sb, Mb, Mm, rho, Hf, Hh, rs, lmv, pbuf, stream);
  } else {
    prep_kernel<false><<<GRID, 256, 0, stream>>>(scores, Mm, Sb, Mb, rs0, pbuf);
    run_steps<false,false>(scores, Sb, Mb, Mm, rho, Hf, Hh, rs, lmv, pbuf, stream);
  }
}